// Round 6
// baseline (527.151 us; speedup 1.0000x reference)
//
#include <hip/hip_runtime.h>
#include <cstdint>
#include <cstddef>

// PureCartesianTensorProduct: B=4096, C1=C2=COUT=64, LMAX=2, FEAT=832, 15 paths.
// out[z,c,m] = sum_p sum_ab W_p[c,a,b] * T_p,m[z,a,b].
// MFMA f32_32x32x16_f16. A = W pre-swizzled in A-frag order (global, L2-hot,
// 2-deep even/odd register prefetch).
//
// R6 structure -- BARRIER-FREE compute. R0/R2/R4/R5 post-mortems: four wave
// shapes all pinned at 309-326 us / 24-25% MfmaUtil; the shared element was
// per-chunk barriered staging (lockstep waves -> MFMA 69us + VALU 77us +
// ~170us neither-pipe). Fix: stage x2 ONCE per block as plain f16 X2[64][834]
// (104 KB LDS, odd-word stride for bank spread), ONE barrier, then all chunks
// run with NO barriers: B-fragments gathered per chunk via scalar ds_read_u16
// (template<NT,D2> -> compile-time offsets), x1 scalars straight from global
// (L1-resident rows, 2-step prefetch). Waves de-phase freely.
// Block = 512 threads = 8 waves = (cgroup 0/1) x (a-quarter 0..3): wave owns
// 32 c-rows, 16 a-steps, ALL 64 z (2 accs) -> W slice read once per
// chunk-block (2.6 GB L2 total). a-quarter partials summed via one LDS
// exchange (D aliases X2 after a barrier). Direct out writes, no gather.
// __launch_bounds__(512,2): reg cap 256 (R1/R3 lesson: never lower; R4's
// identical frag shape measured 128 VGPR spill-free). LDS 105 KB -> 1
// block/CU, 2 waves/SIMD.

#define FEAT 832
#define ZT 64
#define X2S 834   // f16 row stride: odd word count (417) -> lanes spread banks

typedef _Float16 half8 __attribute__((ext_vector_type(8)));
typedef _Float16 half2v __attribute__((ext_vector_type(2)));
typedef float floatx16 __attribute__((ext_vector_type(16)));

struct Chunk {
  int wbase;      // p * 262144, element offset into swizzled f16 weight
  int o1[3];      // absolute x1 feature offset for term t (at a=0)
  int o2[3];      // absolute x2 feature offset for term t (at b=0)
  float sg[3];    // +-1
  int d1, d2, nt; // a-stride (3^L1), b-stride (3^L2), #terms (<=3)
};

// Swizzle W f32 [p][c][k] -> f16 A-frag order:
// Wsw[((p*256 + ksg)*2 + cgrp)*512 + lane*8 + j] = W_p[cgrp*32+(lane&31)][ksg*16+(lane>>5)*8+j]
__global__ void swz_w_kernel(const float* __restrict__ w, _Float16* __restrict__ o) {
  const int i = blockIdx.x * 256 + threadIdx.x;     // one half8 chunk per thread
  const int lane = i & 63;
  const int pkc  = i >> 6;
  const int cgrp = pkc & 1;
  const int ksg  = (pkc >> 1) & 255;
  const int p    = pkc >> 9;
  const int c  = cgrp * 32 + (lane & 31);
  const int k0 = ksg * 16 + (lane >> 5) * 8;
  const float* src = w + (size_t)p * 262144 + (size_t)c * 4096 + k0;
  const float4 v0 = *(const float4*)(src);
  const float4 v1 = *(const float4*)(src + 4);
  half8 h = { (_Float16)v0.x, (_Float16)v0.y, (_Float16)v0.z, (_Float16)v0.w,
              (_Float16)v1.x, (_Float16)v1.y, (_Float16)v1.z, (_Float16)v1.w };
  *(half8*)(o + (size_t)i * 8) = h;
}

__device__ __forceinline__ half8 splat8(_Float16 h) {
  return half8{h, h, h, h, h, h, h, h};
}

// Wave (cg, aq): a in [a0, a0+16), all 64 z. acc0 = zg0 (z 0..31), acc1 = zg1.
// x2 B-fragments gathered from X2 once per chunk (scalar u16, compile-time D2
// offsets). x1 scalars from global with 2-step prefetch. W: 2-deep even/odd.
template<int NT, int D2>
__device__ __forceinline__ void run_chunk(
    const Chunk C, const int zbase, const int ln31, const int hf,
    const int lane, const int cg, const int a0,
    const float* __restrict__ x1, const _Float16* __restrict__ Wh,
    const _Float16* __restrict__ X2,
    floatx16& acc0, floatx16& acc1)
{
  // x2 register fragments [t][zg][ks]
  half8 x2r[NT][2][4];
  #pragma unroll
  for (int t = 0; t < NT; ++t) {
    #pragma unroll
    for (int zg = 0; zg < 2; ++zg) {
      const _Float16* row = X2 + (zg * 32 + ln31) * X2S + C.o2[t] + hf * 8 * D2;
      #pragma unroll
      for (int ks = 0; ks < 4; ++ks) {
        half8 v;
        #pragma unroll
        for (int j = 0; j < 8; ++j) v[j] = row[(ks * 16 + j) * D2];
        x2r[t][zg][ks] = v;
      }
    }
  }

  const _Float16* __restrict__ Wq = Wh + C.wbase + cg * 512 + lane * 8;
  const float* __restrict__ x1r0 = x1 + (size_t)(zbase + ln31) * FEAT;
  const float* __restrict__ x1r1 = x1 + (size_t)(zbase + 32 + ln31) * FEAT;

  // 2-deep W prefetch: even/odd a buffers, this wave's c-group only
  half8 afE[4], afO[4];
  const _Float16* __restrict__ w0 = Wq + (size_t)a0 * 4096;
  #pragma unroll
  for (int ks = 0; ks < 4; ++ks) {
    afE[ks] = *(const half8*)(w0 + ks * 1024);
    afO[ks] = *(const half8*)(w0 + 4096 + ks * 1024);
  }
  float sc[NT][2], scn[NT][2];
  #pragma unroll
  for (int t = 0; t < NT; ++t) {
    const int o1 = C.o1[t];
    sc[t][0]  = x1r0[o1 + a0 * C.d1];
    sc[t][1]  = x1r1[o1 + a0 * C.d1];
    scn[t][0] = x1r0[o1 + (a0 + 1) * C.d1];
    scn[t][1] = x1r1[o1 + (a0 + 1) * C.d1];
  }

  const int aend = a0 + 16;
  #pragma unroll 1
  for (int a = a0; a < aend; a += 2) {
    {  // even: compute a, prefetch a+2
      half8 sv[NT][2];
      #pragma unroll
      for (int t = 0; t < NT; ++t) {
        sv[t][0] = splat8((_Float16)(sc[t][0] * C.sg[t]));
        sv[t][1] = splat8((_Float16)(sc[t][1] * C.sg[t]));
      }
      if (a + 2 < aend) {
        #pragma unroll
        for (int t = 0; t < NT; ++t) {
          sc[t][0] = x1r0[C.o1[t] + (a + 2) * C.d1];
          sc[t][1] = x1r1[C.o1[t] + (a + 2) * C.d1];
        }
      }
      __builtin_amdgcn_s_setprio(1);
      #pragma unroll
      for (int ks = 0; ks < 4; ++ks) {
        half8 tb0 = sv[0][0] * x2r[0][0][ks];
        half8 tb1 = sv[0][1] * x2r[0][1][ks];
        if (NT > 1) { tb0 += sv[1][0] * x2r[1][0][ks]; tb1 += sv[1][1] * x2r[1][1][ks]; }
        if (NT > 2) { tb0 += sv[2][0] * x2r[2][0][ks]; tb1 += sv[2][1] * x2r[2][1][ks]; }
        acc0 = __builtin_amdgcn_mfma_f32_32x32x16_f16(afE[ks], tb0, acc0, 0, 0, 0);
        acc1 = __builtin_amdgcn_mfma_f32_32x32x16_f16(afE[ks], tb1, acc1, 0, 0, 0);
      }
      __builtin_amdgcn_s_setprio(0);
      if (a + 2 < aend) {
        const _Float16* wn = Wq + (size_t)(a + 2) * 4096;
        #pragma unroll
        for (int ks = 0; ks < 4; ++ks)
          afE[ks] = *(const half8*)(wn + ks * 1024);
      }
    }
    {  // odd: compute a+1, prefetch a+3
      half8 sv[NT][2];
      #pragma unroll
      for (int t = 0; t < NT; ++t) {
        sv[t][0] = splat8((_Float16)(scn[t][0] * C.sg[t]));
        sv[t][1] = splat8((_Float16)(scn[t][1] * C.sg[t]));
      }
      if (a + 3 < aend) {
        #pragma unroll
        for (int t = 0; t < NT; ++t) {
          scn[t][0] = x1r0[C.o1[t] + (a + 3) * C.d1];
          scn[t][1] = x1r1[C.o1[t] + (a + 3) * C.d1];
        }
      }
      __builtin_amdgcn_s_setprio(1);
      #pragma unroll
      for (int ks = 0; ks < 4; ++ks) {
        half8 tb0 = sv[0][0] * x2r[0][0][ks];
        half8 tb1 = sv[0][1] * x2r[0][1][ks];
        if (NT > 1) { tb0 += sv[1][0] * x2r[1][0][ks]; tb1 += sv[1][1] * x2r[1][1][ks]; }
        if (NT > 2) { tb0 += sv[2][0] * x2r[2][0][ks]; tb1 += sv[2][1] * x2r[2][1][ks]; }
        acc0 = __builtin_amdgcn_mfma_f32_32x32x16_f16(afO[ks], tb0, acc0, 0, 0, 0);
        acc1 = __builtin_amdgcn_mfma_f32_32x32x16_f16(afO[ks], tb1, acc1, 0, 0, 0);
      }
      __builtin_amdgcn_s_setprio(0);
      if (a + 3 < aend) {
        const _Float16* wn = Wq + (size_t)(a + 3) * 4096;
        #pragma unroll
        for (int ks = 0; ks < 4; ++ks)
          afO[ks] = *(const half8*)(wn + ks * 1024);
      }
    }
  }
}

__global__ __launch_bounds__(512, 2) void tp_kernel(
    const float* __restrict__ x1, const float* __restrict__ x2,
    const _Float16* __restrict__ Wh, float* __restrict__ out)
{
  __shared__ __align__(16) _Float16 X2[64 * X2S];  // 106,752 B (gfx950 LDS 160K)
  __shared__ Chunk chs[7];
  __shared__ int nch_s;

  const int tid  = threadIdx.x;
  const int slot = blockIdx.y;           // 0: L0; 1..3: L1 m; 4..12: L2 (u,v)
  const int zbase = blockIdx.x * ZT;
  const int wid  = tid >> 6;             // 0..7
  const int cg   = wid & 1;              // c-group: rows cg*32 .. cg*32+31
  const int aq   = wid >> 1;             // a-quarter: a in [aq*16, aq*16+16)
  const int a0   = aq * 16;
  const int lane = tid & 63;
  const int ln31 = lane & 31;
  const int hf   = lane >> 5;

  int offO, dO, mO;
  if (slot == 0)      { offO = 0;   dO = 1; mO = 0; }
  else if (slot < 4)  { offO = 64;  dO = 3; mO = slot - 1; }
  else                { offO = 256; dO = 9; mO = slot - 4; }

  if (tid == 0) {
    int n = 0;
    auto add = [&](int p, int L1, int L2,
                   int i0, int i1, int i2, int j0, int j1, int j2,
                   float s0, float s1, float s2, int nt) {
      const int offs[3] = {0, 64, 256};
      const int ds[3]   = {1, 3, 9};
      Chunk c;
      c.wbase = p * 262144;
      c.o1[0] = offs[L1] + i0; c.o1[1] = offs[L1] + i1; c.o1[2] = offs[L1] + i2;
      c.o2[0] = offs[L2] + j0; c.o2[1] = offs[L2] + j1; c.o2[2] = offs[L2] + j2;
      c.sg[0] = s0; c.sg[1] = s1; c.sg[2] = s2;
      c.d1 = ds[L1]; c.d2 = ds[L2]; c.nt = nt;
      chs[n++] = c;
    };
    if (slot == 0) {
      add(0, 0,0, 0,0,0, 0,0,0, 1,0,0, 1);                  // A0*B0
      add(5, 1,1, 0,1,2, 0,1,2, 1,1,1, 3);                  // sum_e A1[e]B1[e]
      add(13,2,2, 0,1,2, 0,1,2, 1,1,1, 3);                  // sum_g A2[g]B2[g] (3 chunks)
      add(13,2,2, 3,4,5, 3,4,5, 1,1,1, 3);
      add(13,2,2, 6,7,8, 6,7,8, 1,1,1, 3);
    } else if (slot < 4) {
      const int m = slot - 1, p1 = (m+1)%3, p2 = (m+2)%3;
      add(1, 0,1, 0,0,0, m,0,0, 1,0,0, 1);                  // A0*B1[m]
      add(3, 1,0, m,0,0, 0,0,0, 1,0,0, 1);                  // A1[m]*B0
      add(6, 1,1, p1,p2,0, p2,p1,0, 1,-1,0, 2);             // eps(m,x,y)A1[x]B1[y]
      add(7, 1,2, 0,1,2, 3*m,3*m+1,3*m+2, 1,1,1, 3);        // sum_e A1[e]B2[m,e]
      add(10,2,1, 3*m,3*m+1,3*m+2, 0,1,2, 1,1,1, 3);        // sum_e A2[m,e]B1[e]
      add(14,2,2, 3*p1,3*p1+1,3*p1+2, 3*p2,3*p2+1,3*p2+2, 1,1,1, 3);    // +A2[p1,e]B2[p2,e]
      add(14,2,2, 3*p2,3*p2+1,3*p2+2, 3*p1,3*p1+1,3*p1+2, -1,-1,-1, 3); // -A2[p2,e]B2[p1,e]
    } else {
      const int m = slot - 4, u = m/3, v = m%3, q1 = (v+1)%3, q2 = (v+2)%3;
      add(2, 0,2, 0,0,0, m,0,0, 1,0,0, 1);                  // A0*B2[u,v]
      add(4, 1,1, u,0,0, v,0,0, 1,0,0, 1);                  // A1[u]*B1[v]
      add(8, 1,2, q1,q2,0, 3*u+q2,3*u+q1,0, 1,-1,0, 2);     // eps(v,x,y)A1[x]B2[u,y]
      add(9, 2,0, m,0,0, 0,0,0, 1,0,0, 1);                  // A2[u,v]*B0
      add(11,2,1, 3*u+q1,3*u+q2,0, q2,q1,0, 1,-1,0, 2);     // eps(v,e,f)A2[u,e]B1[f]
      add(12,2,2, 3*u,3*u+1,3*u+2, 3*v,3*v+1,3*v+2, 1,1,1, 3); // sum_e A2[u,e]B2[v,e]
    }
    nch_s = n;
  }

  // one-time x2 staging: f32 -> f16 table X2[z][f], coalesced float2 per lane
  for (int row = wid; row < 64; row += 8) {
    const float* __restrict__ src = x2 + (size_t)(zbase + row) * FEAT;
    _Float16* __restrict__ dst = X2 + row * X2S;
    #pragma unroll
    for (int k = 0; k < 7; ++k) {
      const int f = k * 128 + lane * 2;
      if (f < FEAT) {
        const float2 v = *(const float2*)(src + f);
        half2v h = { (_Float16)v.x, (_Float16)v.y };
        *(half2v*)(dst + f) = h;   // 4B-aligned: row*X2S even, f even
      }
    }
  }
  __syncthreads();   // the ONLY barrier before the reduction
  const int nch = nch_s;

  floatx16 acc0, acc1;   // zg0 / zg1 for this wave's (cg, a-quarter)
  #pragma unroll
  for (int r = 0; r < 16; ++r) { acc0[r] = 0.0f; acc1[r] = 0.0f; }

  for (int ci = 0; ci < nch; ++ci) {
    const Chunk C = chs[ci];  // block-uniform
    const int key = C.nt * 16 + C.d2;
    switch (key) {
      case 17: run_chunk<1,1>(C, zbase, ln31, hf, lane, cg, a0, x1, Wh, X2, acc0, acc1); break;
      case 19: run_chunk<1,3>(C, zbase, ln31, hf, lane, cg, a0, x1, Wh, X2, acc0, acc1); break;
      case 25: run_chunk<1,9>(C, zbase, ln31, hf, lane, cg, a0, x1, Wh, X2, acc0, acc1); break;
      case 35: run_chunk<2,3>(C, zbase, ln31, hf, lane, cg, a0, x1, Wh, X2, acc0, acc1); break;
      case 41: run_chunk<2,9>(C, zbase, ln31, hf, lane, cg, a0, x1, Wh, X2, acc0, acc1); break;
      case 51: run_chunk<3,3>(C, zbase, ln31, hf, lane, cg, a0, x1, Wh, X2, acc0, acc1); break;
      default: run_chunk<3,9>(C, zbase, ln31, hf, lane, cg, a0, x1, Wh, X2, acc0, acc1); break;
    }
  }

  // cross-wave reduction over a-quarters: aq>0 dump, aq==0 adds + stores.
  // D[(cg*3 + (aq-1))*2 + zg][r][lane] f32 = 48 KB, aliases X2 (all reads done).
  __syncthreads();
  float* Dv = (float*)X2;
  if (aq > 0) {
    const int b = (cg * 3 + (aq - 1)) * 2048;
    #pragma unroll
    for (int r = 0; r < 16; ++r) {
      Dv[b + r * 64 + lane]        = acc0[r];
      Dv[b + 1024 + r * 64 + lane] = acc1[r];
    }
  }
  __syncthreads();
  if (aq == 0) {
    #pragma unroll
    for (int j = 0; j < 3; ++j) {
      const int b = (cg * 3 + j) * 2048;
      #pragma unroll
      for (int r = 0; r < 16; ++r) {
        acc0[r] += Dv[b + r * 64 + lane];
        acc1[r] += Dv[b + 1024 + r * 64 + lane];
      }
    }
    // epilogue: C/D 32x32 layout: col(z)=lane&31, row(c)=(r&3)+8*(r>>2)+4*hf.
    float* __restrict__ op0 = out + (size_t)(zbase + ln31) * FEAT + offO + mO;
    float* __restrict__ op1 = out + (size_t)(zbase + 32 + ln31) * FEAT + offO + mO;
    #pragma unroll
    for (int r = 0; r < 16; ++r) {
      const int cr = cg * 32 + (r & 3) + 8 * (r >> 2) + 4 * hf;
      op0[(size_t)cr * dO] = acc0[r];
      op1[(size_t)cr * dO] = acc1[r];
    }
  }
}

extern "C" void kernel_launch(void* const* d_in, const int* in_sizes, int n_in,
                              void* d_out, int out_size, void* d_ws, size_t ws_size,
                              hipStream_t stream) {
  const float* x1 = (const float*)d_in[0];
  const float* x2 = (const float*)d_in[1];
  const float* w  = (const float*)d_in[2];
  float* out = (float*)d_out;
  _Float16* Wh = (_Float16*)d_ws;            // 15*64*4096 f16 = 7,864,320 B (swizzled)

  const int nchunks = 15 * 64 * 4096 / 8;    // 491520 half8 chunks
  hipLaunchKernelGGL(swz_w_kernel, dim3(nchunks / 256), dim3(256), 0, stream, w, Wh);

  dim3 grid(64, 13);          // z-tiles x slots
  hipLaunchKernelGGL(tp_kernel, grid, dim3(512), 0, stream, x1, x2, Wh, out);
}

// Round 7
// 479.775 us; speedup vs baseline: 1.0987x; 1.0987x over previous
//
#include <hip/hip_runtime.h>
#include <cstdint>
#include <cstddef>

// PureCartesianTensorProduct: B=4096, C1=C2=COUT=64, LMAX=2, FEAT=832, 15 paths.
// out[z,c,m] = sum_p sum_ab W_p[c,a,b] * T_p,m[z,a,b].
// MFMA f32_32x32x16_f16. A = W pre-swizzled in A-frag order (global, L2-hot,
// 2-deep even/odd register prefetch).
//
// R7: T14 async-STAGE split on the proven R5 dataflow.
// R5 post-mortem: per-chunk staging put the FULL global-load latency chain
// inside the barrier window, and the 3 co-resident blocks (identical chunk
// sequences, same start) stayed phase-locked -> CU oscillated load-burst /
// MFMA-burst, ~50% both-pipes-idle, 24% MfmaUtil across 4 structures.
// R6 regression isolated the rule: compute-loop operands must be reg/LDS.
// Fix here:
//  - issue chunk ci+1's 48 scattered global loads into REGISTERS before ci's
//    a-loop (drain under ~4000 cyc of MFMA); barrier window shrinks to
//    convert+ds_write+barrier (~600 cyc).
//  - 512-thread blocks: 8 waves = zgrp(2) x a-quarter(4), 16 a-steps each;
//    pending regs 48 f32/thread; same 53 KB LDS -> 3 blocks/CU, 24 waves/CU.
//  - chunk order rotated by blockIdx.x (chunks commute) -> blocks de-phase.
//  - staging loops: #pragma unroll + wave-uniform if(t<nt) -> static reg idx.
// a-quarter partials summed via LDS exchange (Dv aliases XS after last read).
// __launch_bounds__(512,2): reg cap 256 (R1/R3: never lower).

#define FEAT 832
#define ZT 64

typedef _Float16 half8 __attribute__((ext_vector_type(8)));
typedef float floatx16 __attribute__((ext_vector_type(16)));

struct Chunk {
  int wbase;      // p * 262144, element offset into swizzled f16 weight
  int o1[3];      // absolute x1 feature offset for term t (at a=0)
  int o2[3];      // absolute x2 feature offset for term t (at b=0)
  float sg[3];    // +-1
  int d1, d2, nt; // a-stride (3^L1), b-stride (3^L2), #terms (<=3)
};

// Swizzle W f32 [p][c][k] -> f16 A-frag order:
// Wsw[((p*256 + ksg)*2 + cgrp)*512 + lane*8 + j] = W_p[cgrp*32+(lane&31)][ksg*16+(lane>>5)*8+j]
__global__ void swz_w_kernel(const float* __restrict__ w, _Float16* __restrict__ o) {
  const int i = blockIdx.x * 256 + threadIdx.x;     // one half8 chunk per thread
  const int lane = i & 63;
  const int pkc  = i >> 6;
  const int cgrp = pkc & 1;
  const int ksg  = (pkc >> 1) & 255;
  const int p    = pkc >> 9;
  const int c  = cgrp * 32 + (lane & 31);
  const int k0 = ksg * 16 + (lane >> 5) * 8;
  const float* src = w + (size_t)p * 262144 + (size_t)c * 4096 + k0;
  const float4 v0 = *(const float4*)(src);
  const float4 v1 = *(const float4*)(src + 4);
  half8 h = { (_Float16)v0.x, (_Float16)v0.y, (_Float16)v0.z, (_Float16)v0.w,
              (_Float16)v1.x, (_Float16)v1.y, (_Float16)v1.z, (_Float16)v1.w };
  *(half8*)(o + (size_t)i * 8) = h;
}

__device__ __forceinline__ half8 splat8(_Float16 h) {
  return half8{h, h, h, h, h, h, h, h};
}

struct StageRegs {
  float r2[3][8];   // x2 elements: e = tid + k*512 -> zz=e>>6, b=e&63
  float r1[3][8];   // x1 elements: same e -> zz=e>>6, a=e&63
};

// Issue the scattered global loads for chunk C into registers (no LDS touch).
__device__ __forceinline__ void issue_loads(
    const Chunk& C, const int zbase, const int tid,
    const float* __restrict__ x1, const float* __restrict__ x2, StageRegs& S)
{
  #pragma unroll
  for (int t = 0; t < 3; ++t) {
    if (t < C.nt) {
      const int o2 = C.o2[t], o1 = C.o1[t];
      #pragma unroll
      for (int k = 0; k < 8; ++k) {
        const int e = tid + k * 512;
        const int zz = e >> 6, b = e & 63;
        const size_t row = (size_t)(zbase + zz) * FEAT;
        S.r2[t][k] = x2[row + o2 + b * C.d2];
        S.r1[t][k] = x1[row + o1 + b * C.d1];
      }
    }
  }
}

// Convert + write the pending registers into the LDS staging buffers.
// XS2: [t][zz]*72+b f16. XS1: [t][a]*66+zz f16 (x1 pre-scaled by sg).
__device__ __forceinline__ void write_stage(
    const Chunk& C, const int tid, const StageRegs& S,
    _Float16* __restrict__ XS2, _Float16* __restrict__ XS1)
{
  #pragma unroll
  for (int t = 0; t < 3; ++t) {
    if (t < C.nt) {
      const float sg = C.sg[t];
      #pragma unroll
      for (int k = 0; k < 8; ++k) {
        const int e = tid + k * 512;
        const int zz = e >> 6, b = e & 63;
        XS2[(t * 64 + zz) * 72 + b] = (_Float16)S.r2[t][k];
        XS1[(t * 64 + b) * 66 + zz] = (_Float16)(S.r1[t][k] * sg);
      }
    }
  }
}

// Compute this wave's 16 a-steps for chunk C from LDS. R5 inner loop verbatim
// (2-deep even/odd W prefetch, sc scalar prefetch from LDS, setprio on MFMA).
template<int NT>
__device__ __forceinline__ void run_compute(
    const Chunk C, const int zl, const int hf, const int lane, const int a0,
    const _Float16* __restrict__ Wh,
    const _Float16* __restrict__ XS2, const _Float16* __restrict__ XS1,
    floatx16& acc0, floatx16& acc1)
{
  // a-invariant x2 register fragments (ds_read_b128)
  half8 x2r[NT][4];
  #pragma unroll
  for (int t = 0; t < NT; ++t) {
    #pragma unroll
    for (int ks = 0; ks < 4; ++ks)
      x2r[t][ks] = *(const half8*)&XS2[(t * 64 + zl) * 72 + ks * 16 + hf * 8];
  }

  const _Float16* __restrict__ Wq = Wh + C.wbase + lane * 8;
  const _Float16* __restrict__ Xq = XS1 + zl;

  // 2-deep W prefetch: even/odd a buffers, [cgrp][ks]
  half8 afE[2][4], afO[2][4];
  const _Float16* __restrict__ w0 = Wq + (size_t)a0 * 4096;
  #pragma unroll
  for (int ks = 0; ks < 4; ++ks) {
    afE[0][ks] = *(const half8*)(w0 + ks * 1024);
    afE[1][ks] = *(const half8*)(w0 + ks * 1024 + 512);
    afO[0][ks] = *(const half8*)(w0 + 4096 + ks * 1024);
    afO[1][ks] = *(const half8*)(w0 + 4096 + ks * 1024 + 512);
  }
  _Float16 sc[NT], scn[NT];
  #pragma unroll
  for (int t = 0; t < NT; ++t) {
    sc[t]  = Xq[(t * 64 + a0) * 66];
    scn[t] = Xq[(t * 64 + a0 + 1) * 66];
  }

  const int aend = a0 + 16;
  #pragma unroll 1
  for (int a = a0; a < aend; a += 2) {
    {  // even: compute a, prefetch a+2
      half8 sv[NT];
      #pragma unroll
      for (int t = 0; t < NT; ++t) sv[t] = splat8(sc[t]);
      if (a + 2 < aend) {
        #pragma unroll
        for (int t = 0; t < NT; ++t) sc[t] = Xq[(t * 64 + a + 2) * 66];
      }
      __builtin_amdgcn_s_setprio(1);
      #pragma unroll
      for (int ks = 0; ks < 4; ++ks) {
        half8 tb = sv[0] * x2r[0][ks];
        if (NT > 1) tb += sv[1] * x2r[1][ks];
        if (NT > 2) tb += sv[2] * x2r[2][ks];
        acc0 = __builtin_amdgcn_mfma_f32_32x32x16_f16(afE[0][ks], tb, acc0, 0, 0, 0);
        acc1 = __builtin_amdgcn_mfma_f32_32x32x16_f16(afE[1][ks], tb, acc1, 0, 0, 0);
      }
      __builtin_amdgcn_s_setprio(0);
      if (a + 2 < aend) {
        const _Float16* wn = Wq + (size_t)(a + 2) * 4096;
        #pragma unroll
        for (int ks = 0; ks < 4; ++ks) {
          afE[0][ks] = *(const half8*)(wn + ks * 1024);
          afE[1][ks] = *(const half8*)(wn + ks * 1024 + 512);
        }
      }
    }
    {  // odd: compute a+1, prefetch a+3
      half8 sv[NT];
      #pragma unroll
      for (int t = 0; t < NT; ++t) sv[t] = splat8(scn[t]);
      if (a + 3 < aend) {
        #pragma unroll
        for (int t = 0; t < NT; ++t) scn[t] = Xq[(t * 64 + a + 3) * 66];
      }
      __builtin_amdgcn_s_setprio(1);
      #pragma unroll
      for (int ks = 0; ks < 4; ++ks) {
        half8 tb = sv[0] * x2r[0][ks];
        if (NT > 1) tb += sv[1] * x2r[1][ks];
        if (NT > 2) tb += sv[2] * x2r[2][ks];
        acc0 = __builtin_amdgcn_mfma_f32_32x32x16_f16(afO[0][ks], tb, acc0, 0, 0, 0);
        acc1 = __builtin_amdgcn_mfma_f32_32x32x16_f16(afO[1][ks], tb, acc1, 0, 0, 0);
      }
      __builtin_amdgcn_s_setprio(0);
      if (a + 3 < aend) {
        const _Float16* wn = Wq + (size_t)(a + 3) * 4096;
        #pragma unroll
        for (int ks = 0; ks < 4; ++ks) {
          afO[0][ks] = *(const half8*)(wn + ks * 1024);
          afO[1][ks] = *(const half8*)(wn + ks * 1024 + 512);
        }
      }
    }
  }
}

__global__ __launch_bounds__(512, 2) void tp_kernel(
    const float* __restrict__ x1, const float* __restrict__ x2,
    const _Float16* __restrict__ Wh, float* __restrict__ out)
{
  // XS2 27648 B + XS1 25344 B = 52992 B; Dv (49152 B) aliases it at the end.
  __shared__ __align__(16) char SH[52992];
  _Float16* __restrict__ XS2 = (_Float16*)SH;
  _Float16* __restrict__ XS1 = (_Float16*)(SH + 27648);
  __shared__ Chunk chs[7];
  __shared__ int nch_s;

  const int tid  = threadIdx.x;
  const int slot = blockIdx.y;           // 0: L0; 1..3: L1 m; 4..12: L2 (u,v)
  const int zbase = blockIdx.x * ZT;
  const int wid  = tid >> 6;             // 0..7
  const int zgrp = wid & 1;              // z-group (32 z each)
  const int aq   = wid >> 1;             // a-quarter: a in [aq*16, aq*16+16)
  const int a0   = aq * 16;
  const int lane = tid & 63;
  const int ln31 = lane & 31;
  const int hf   = lane >> 5;
  const int zl   = zgrp * 32 + ln31;     // B-frag col z within tile

  int offO, dO, mO;
  if (slot == 0)      { offO = 0;   dO = 1; mO = 0; }
  else if (slot < 4)  { offO = 64;  dO = 3; mO = slot - 1; }
  else                { offO = 256; dO = 9; mO = slot - 4; }

  if (tid == 0) {
    int n = 0;
    auto add = [&](int p, int L1, int L2,
                   int i0, int i1, int i2, int j0, int j1, int j2,
                   float s0, float s1, float s2, int nt) {
      const int offs[3] = {0, 64, 256};
      const int ds[3]   = {1, 3, 9};
      Chunk c;
      c.wbase = p * 262144;
      c.o1[0] = offs[L1] + i0; c.o1[1] = offs[L1] + i1; c.o1[2] = offs[L1] + i2;
      c.o2[0] = offs[L2] + j0; c.o2[1] = offs[L2] + j1; c.o2[2] = offs[L2] + j2;
      c.sg[0] = s0; c.sg[1] = s1; c.sg[2] = s2;
      c.d1 = ds[L1]; c.d2 = ds[L2]; c.nt = nt;
      chs[n++] = c;
    };
    if (slot == 0) {
      add(0, 0,0, 0,0,0, 0,0,0, 1,0,0, 1);                  // A0*B0
      add(5, 1,1, 0,1,2, 0,1,2, 1,1,1, 3);                  // sum_e A1[e]B1[e]
      add(13,2,2, 0,1,2, 0,1,2, 1,1,1, 3);                  // sum_g A2[g]B2[g] (3 chunks)
      add(13,2,2, 3,4,5, 3,4,5, 1,1,1, 3);
      add(13,2,2, 6,7,8, 6,7,8, 1,1,1, 3);
    } else if (slot < 4) {
      const int m = slot - 1, p1 = (m+1)%3, p2 = (m+2)%3;
      add(1, 0,1, 0,0,0, m,0,0, 1,0,0, 1);                  // A0*B1[m]
      add(3, 1,0, m,0,0, 0,0,0, 1,0,0, 1);                  // A1[m]*B0
      add(6, 1,1, p1,p2,0, p2,p1,0, 1,-1,0, 2);             // eps(m,x,y)A1[x]B1[y]
      add(7, 1,2, 0,1,2, 3*m,3*m+1,3*m+2, 1,1,1, 3);        // sum_e A1[e]B2[m,e]
      add(10,2,1, 3*m,3*m+1,3*m+2, 0,1,2, 1,1,1, 3);        // sum_e A2[m,e]B1[e]
      add(14,2,2, 3*p1,3*p1+1,3*p1+2, 3*p2,3*p2+1,3*p2+2, 1,1,1, 3);    // +A2[p1,e]B2[p2,e]
      add(14,2,2, 3*p2,3*p2+1,3*p2+2, 3*p1,3*p1+1,3*p1+2, -1,-1,-1, 3); // -A2[p2,e]B2[p1,e]
    } else {
      const int m = slot - 4, u = m/3, v = m%3, q1 = (v+1)%3, q2 = (v+2)%3;
      add(2, 0,2, 0,0,0, m,0,0, 1,0,0, 1);                  // A0*B2[u,v]
      add(4, 1,1, u,0,0, v,0,0, 1,0,0, 1);                  // A1[u]*B1[v]
      add(8, 1,2, q1,q2,0, 3*u+q2,3*u+q1,0, 1,-1,0, 2);     // eps(v,x,y)A1[x]B2[u,y]
      add(9, 2,0, m,0,0, 0,0,0, 1,0,0, 1);                  // A2[u,v]*B0
      add(11,2,1, 3*u+q1,3*u+q2,0, q2,q1,0, 1,-1,0, 2);     // eps(v,e,f)A2[u,e]B1[f]
      add(12,2,2, 3*u,3*u+1,3*u+2, 3*v,3*v+1,3*v+2, 1,1,1, 3); // sum_e A2[u,e]B2[v,e]
    }
    nch_s = n;
  }
  __syncthreads();
  const int nch = nch_s;

  floatx16 acc0, acc1;
  #pragma unroll
  for (int r = 0; r < 16; ++r) { acc0[r] = 0.0f; acc1[r] = 0.0f; }

  // chunk order rotated by blockIdx.x: chunks commute, co-resident blocks
  // de-phase instead of bursting loads / MFMA in lockstep.
  const int rot = blockIdx.x % nch;
  StageRegs S;
  issue_loads(chs[rot], zbase, tid, x1, x2, S);

  for (int k = 0; k < nch; ++k) {
    const int ci = (k + rot) < nch ? (k + rot) : (k + rot - nch);
    const Chunk C = chs[ci];  // block-uniform
    // S holds chunk ci's data (issued last iteration): publish to LDS.
    __syncthreads();           // previous chunk's LDS readers done
    write_stage(C, tid, S, XS2, XS1);   // waits vmcnt internally (reg use)
    __syncthreads();
    if (k + 1 < nch) {
      const int cn = (ci + 1) < nch ? (ci + 1) : 0;
      issue_loads(chs[cn], zbase, tid, x1, x2, S);  // drains under compute
    }
    if (C.nt == 1)      run_compute<1>(C, zl, hf, lane, a0, Wh, XS2, XS1, acc0, acc1);
    else if (C.nt == 2) run_compute<2>(C, zl, hf, lane, a0, Wh, XS2, XS1, acc0, acc1);
    else                run_compute<3>(C, zl, hf, lane, a0, Wh, XS2, XS1, acc0, acc1);
  }

  // cross-wave reduction over a-quarters: aq>0 dump, aq==0 adds + stores.
  // Dv group = ((aq-1)*2 + zgrp)*2 + accid, 1024 f32 each: 12 KB*4 = 48 KB.
  __syncthreads();   // all waves done reading XS1/XS2
  float* __restrict__ Dv = (float*)SH;
  if (aq > 0) {
    const int b0 = (((aq - 1) * 2 + zgrp) * 2 + 0) * 1024;
    const int b1 = (((aq - 1) * 2 + zgrp) * 2 + 1) * 1024;
    #pragma unroll
    for (int r = 0; r < 16; ++r) {
      Dv[b0 + r * 64 + lane] = acc0[r];
      Dv[b1 + r * 64 + lane] = acc1[r];
    }
  }
  __syncthreads();
  if (aq == 0) {
    #pragma unroll
    for (int j = 1; j < 4; ++j) {
      const int b0 = (((j - 1) * 2 + zgrp) * 2 + 0) * 1024;
      const int b1 = (((j - 1) * 2 + zgrp) * 2 + 1) * 1024;
      #pragma unroll
      for (int r = 0; r < 16; ++r) {
        acc0[r] += Dv[b0 + r * 64 + lane];
        acc1[r] += Dv[b1 + r * 64 + lane];
      }
    }
    // epilogue: C/D 32x32 layout: col(z)=lane&31, row(c)=(r&3)+8*(r>>2)+4*hf.
    float* __restrict__ op = out + (size_t)(zbase + zl) * FEAT + offO + mO;
    #pragma unroll
    for (int r = 0; r < 16; ++r) {
      const int cr = (r & 3) + 8 * (r >> 2) + 4 * hf;
      op[(size_t)cr * dO]        = acc0[r];
      op[(size_t)(cr + 32) * dO] = acc1[r];
    }
  }
}

extern "C" void kernel_launch(void* const* d_in, const int* in_sizes, int n_in,
                              void* d_out, int out_size, void* d_ws, size_t ws_size,
                              hipStream_t stream) {
  const float* x1 = (const float*)d_in[0];
  const float* x2 = (const float*)d_in[1];
  const float* w  = (const float*)d_in[2];
  float* out = (float*)d_out;
  _Float16* Wh = (_Float16*)d_ws;            // 15*64*4096 f16 = 7,864,320 B (swizzled)

  const int nchunks = 15 * 64 * 4096 / 8;    // 491520 half8 chunks
  hipLaunchKernelGGL(swz_w_kernel, dim3(nchunks / 256), dim3(256), 0, stream, w, Wh);

  dim3 grid(64, 13);          // z-tiles x slots
  hipLaunchKernelGGL(tp_kernel, grid, dim3(512), 0, stream, x1, x2, Wh, out);
}

// Round 8
// 450.599 us; speedup vs baseline: 1.1699x; 1.0647x over previous
//
#include <hip/hip_runtime.h>
#include <cstdint>
#include <cstddef>

// PureCartesianTensorProduct: B=4096, C1=C2=COUT=64, LMAX=2, FEAT=832, 15 paths.
// out[z,c,m] = sum_p sum_ab W_p[c,a,b] * T_p,m[z,a,b].
// MFMA f32_32x32x16_f16. A = W pre-swizzled in A-frag order.
//
// R8 theory (R0-R7 post-mortem): every structure kept the same L3 byte flow
// and every one ran ~310-326 us. Two L3 flows dominate:
//  (1) W stream 2.6 GB/dispatch (unique 512 KB x 80 chunks x 64 z-tiles); W =
//      7.8 MB > 4 MB per-XCD L2 -> streams from Infinity Cache at ~8 TB/s
//      effective = the invariant wall. Duplication fixes (R3/R4) were no-ops
//      because duplicate reads were L2-hits; UNIQUE traffic never moved.
//  (2) strided staging line-explosion: d2=9 gathers touch 36 lines per 256
//      useful bytes; x tiles get evicted from L2 by the W stream -> ~2 GB L3.
// R8 fixes:
//  (1) XCD-grouped scheduling: W is m-independent; slots 1-3 share 6 paths
//      (3 MB), slots 4-12 share 6 paths (3 MB), slot 0 uses 3 (1.5 MB).
//      1-D grid 832, u=(bid%8)*104+bid/8, slot=u/64, ztile=u%64: dispatch
//      round-robins wgid%8 -> XCD, so each XCD's blocks draw from a <=3-4.5MB
//      W set -> L2-resident. Wrong-mapping risk degrades to status quo.
//  (2) x2 staged ONCE per block as full-row f16 table X2[64][834] (coalesced,
//      106 KB, bank-shift-1 per row -> conflict-free scalar gathers). x1 stays
//      in per-chunk barriered XS1 (R6 lesson: NO global loads in the a-loop;
//      R7 lesson: NO 48-reg prefetch across compute -> spill).
// Block 512 = 8 waves = zg(2) x aq(4): wave = 32 z, both c-groups, 16 a-steps
// (shared-tb VALU-efficient shape). Regs ~170 nominal (acc 32, x2r 48, af 64).
// LDS 132 KB -> 1 block/CU. aq partials reduced via Dv aliasing X2 at the end.
// __launch_bounds__(512,2) -> 256-reg cap (R1/R3: never lower).

#define FEAT 832
#define X2S 834   // f16 row stride: 417 words; 417%32==1 -> bank+1 per row

typedef _Float16 half8 __attribute__((ext_vector_type(8)));
typedef _Float16 half2v __attribute__((ext_vector_type(2)));
typedef float floatx16 __attribute__((ext_vector_type(16)));

struct Chunk {
  int wbase;      // p * 262144, element offset into swizzled f16 weight
  int o1[3];      // absolute x1 feature offset for term t (at a=0)
  int o2[3];      // absolute x2 feature offset for term t (at b=0)
  float sg[3];    // +-1
  int d1, d2, nt; // a-stride (3^L1), b-stride (3^L2), #terms (<=3)
};

// Swizzle W f32 [p][c][k] -> f16 A-frag order:
// Wsw[((p*256 + ksg)*2 + cgrp)*512 + lane*8 + j] = W_p[cgrp*32+(lane&31)][ksg*16+(lane>>5)*8+j]
__global__ void swz_w_kernel(const float* __restrict__ w, _Float16* __restrict__ o) {
  const int i = blockIdx.x * 256 + threadIdx.x;     // one half8 chunk per thread
  const int lane = i & 63;
  const int pkc  = i >> 6;
  const int cgrp = pkc & 1;
  const int ksg  = (pkc >> 1) & 255;
  const int p    = pkc >> 9;
  const int c  = cgrp * 32 + (lane & 31);
  const int k0 = ksg * 16 + (lane >> 5) * 8;
  const float* src = w + (size_t)p * 262144 + (size_t)c * 4096 + k0;
  const float4 v0 = *(const float4*)(src);
  const float4 v1 = *(const float4*)(src + 4);
  half8 h = { (_Float16)v0.x, (_Float16)v0.y, (_Float16)v0.z, (_Float16)v0.w,
              (_Float16)v1.x, (_Float16)v1.y, (_Float16)v1.z, (_Float16)v1.w };
  *(half8*)(o + (size_t)i * 8) = h;
}

__device__ __forceinline__ half8 splat8(_Float16 h) {
  return half8{h, h, h, h, h, h, h, h};
}

// Compute this wave's 16 a-steps for chunk C. x2 fragments gathered from the
// X2 full-row table (compile-time D2 stride; conflict-free: bank+1 per row).
// x1 scalars from XS1 (LDS, staged in the barrier window). W 2-deep even/odd.
template<int NT, int D2>
__device__ __forceinline__ void run_chunk(
    const Chunk C, const int zl, const int hf, const int lane, const int a0,
    const _Float16* __restrict__ Wh,
    const _Float16* __restrict__ X2, const _Float16* __restrict__ XS1,
    floatx16& acc0, floatx16& acc1)
{
  // x2 register fragments: b = ks*16 + hf*8 + j, element o2 + b*D2
  half8 x2r[NT][4];
  #pragma unroll
  for (int t = 0; t < NT; ++t) {
    const _Float16* __restrict__ row = X2 + zl * X2S + C.o2[t] + hf * 8 * D2;
    #pragma unroll
    for (int ks = 0; ks < 4; ++ks) {
      half8 v;
      #pragma unroll
      for (int j = 0; j < 8; ++j) v[j] = row[(ks * 16 + j) * D2];
      x2r[t][ks] = v;
    }
  }

  const _Float16* __restrict__ Wq = Wh + C.wbase + lane * 8;
  const _Float16* __restrict__ Xq = XS1 + zl;

  // 2-deep W prefetch: even/odd a buffers, [cgrp][ks]
  half8 afE[2][4], afO[2][4];
  const _Float16* __restrict__ w0 = Wq + (size_t)a0 * 4096;
  #pragma unroll
  for (int ks = 0; ks < 4; ++ks) {
    afE[0][ks] = *(const half8*)(w0 + ks * 1024);
    afE[1][ks] = *(const half8*)(w0 + ks * 1024 + 512);
    afO[0][ks] = *(const half8*)(w0 + 4096 + ks * 1024);
    afO[1][ks] = *(const half8*)(w0 + 4096 + ks * 1024 + 512);
  }
  _Float16 sc[NT], scn[NT];
  #pragma unroll
  for (int t = 0; t < NT; ++t) {
    sc[t]  = Xq[(t * 64 + a0) * 66];
    scn[t] = Xq[(t * 64 + a0 + 1) * 66];
  }

  const int aend = a0 + 16;
  #pragma unroll 1
  for (int a = a0; a < aend; a += 2) {
    {  // even: compute a, prefetch a+2
      half8 sv[NT];
      #pragma unroll
      for (int t = 0; t < NT; ++t) sv[t] = splat8(sc[t]);
      if (a + 2 < aend) {
        #pragma unroll
        for (int t = 0; t < NT; ++t) sc[t] = Xq[(t * 64 + a + 2) * 66];
      }
      __builtin_amdgcn_s_setprio(1);
      #pragma unroll
      for (int ks = 0; ks < 4; ++ks) {
        half8 tb = sv[0] * x2r[0][ks];
        if (NT > 1) tb += sv[1] * x2r[1][ks];
        if (NT > 2) tb += sv[2] * x2r[2][ks];
        acc0 = __builtin_amdgcn_mfma_f32_32x32x16_f16(afE[0][ks], tb, acc0, 0, 0, 0);
        acc1 = __builtin_amdgcn_mfma_f32_32x32x16_f16(afE[1][ks], tb, acc1, 0, 0, 0);
      }
      __builtin_amdgcn_s_setprio(0);
      if (a + 2 < aend) {
        const _Float16* wn = Wq + (size_t)(a + 2) * 4096;
        #pragma unroll
        for (int ks = 0; ks < 4; ++ks) {
          afE[0][ks] = *(const half8*)(wn + ks * 1024);
          afE[1][ks] = *(const half8*)(wn + ks * 1024 + 512);
        }
      }
    }
    {  // odd: compute a+1, prefetch a+3
      half8 sv[NT];
      #pragma unroll
      for (int t = 0; t < NT; ++t) sv[t] = splat8(scn[t]);
      if (a + 3 < aend) {
        #pragma unroll
        for (int t = 0; t < NT; ++t) scn[t] = Xq[(t * 64 + a + 3) * 66];
      }
      __builtin_amdgcn_s_setprio(1);
      #pragma unroll
      for (int ks = 0; ks < 4; ++ks) {
        half8 tb = sv[0] * x2r[0][ks];
        if (NT > 1) tb += sv[1] * x2r[1][ks];
        if (NT > 2) tb += sv[2] * x2r[2][ks];
        acc0 = __builtin_amdgcn_mfma_f32_32x32x16_f16(afO[0][ks], tb, acc0, 0, 0, 0);
        acc1 = __builtin_amdgcn_mfma_f32_32x32x16_f16(afO[1][ks], tb, acc1, 0, 0, 0);
      }
      __builtin_amdgcn_s_setprio(0);
      if (a + 3 < aend) {
        const _Float16* wn = Wq + (size_t)(a + 3) * 4096;
        #pragma unroll
        for (int ks = 0; ks < 4; ++ks) {
          afO[0][ks] = *(const half8*)(wn + ks * 1024);
          afO[1][ks] = *(const half8*)(wn + ks * 1024 + 512);
        }
      }
    }
  }
}

__global__ __launch_bounds__(512, 2) void tp_kernel(
    const float* __restrict__ x1, const float* __restrict__ x2,
    const _Float16* __restrict__ Wh, float* __restrict__ out)
{
  __shared__ __align__(16) _Float16 X2[64 * X2S];   // 106,752 B (one-time table)
  __shared__ __align__(16) _Float16 XS1[3 * 64 * 66]; // 25,344 B (per-chunk x1)
  __shared__ Chunk chs[7];
  __shared__ int nch_s;

  const int tid  = threadIdx.x;
  // XCD-grouped work mapping: bid%8 -> XCD (dispatch round-robin), so each
  // XCD draws from a contiguous 104-unit range = 2-3 slots sharing one W set.
  const int bid  = blockIdx.x;
  const int u    = (bid & 7) * 104 + (bid >> 3);
  const int slot = u >> 6;               // 0: L0; 1..3: L1 m; 4..12: L2 (u,v)
  const int zbase = (u & 63) * 64;
  const int wid  = tid >> 6;             // 0..7
  const int zg   = wid & 1;              // z-group (32 z each)
  const int aq   = wid >> 1;             // a-quarter: a in [aq*16, aq*16+16)
  const int a0   = aq * 16;
  const int lane = tid & 63;
  const int ln31 = lane & 31;
  const int hf   = lane >> 5;
  const int zl   = zg * 32 + ln31;       // B-frag col z within tile

  int offO, dO, mO;
  if (slot == 0)      { offO = 0;   dO = 1; mO = 0; }
  else if (slot < 4)  { offO = 64;  dO = 3; mO = slot - 1; }
  else                { offO = 256; dO = 9; mO = slot - 4; }

  if (tid == 0) {
    int n = 0;
    auto add = [&](int p, int L1, int L2,
                   int i0, int i1, int i2, int j0, int j1, int j2,
                   float s0, float s1, float s2, int nt) {
      const int offs[3] = {0, 64, 256};
      const int ds[3]   = {1, 3, 9};
      Chunk c;
      c.wbase = p * 262144;
      c.o1[0] = offs[L1] + i0; c.o1[1] = offs[L1] + i1; c.o1[2] = offs[L1] + i2;
      c.o2[0] = offs[L2] + j0; c.o2[1] = offs[L2] + j1; c.o2[2] = offs[L2] + j2;
      c.sg[0] = s0; c.sg[1] = s1; c.sg[2] = s2;
      c.d1 = ds[L1]; c.d2 = ds[L2]; c.nt = nt;
      chs[n++] = c;
    };
    if (slot == 0) {
      add(0, 0,0, 0,0,0, 0,0,0, 1,0,0, 1);                  // A0*B0
      add(5, 1,1, 0,1,2, 0,1,2, 1,1,1, 3);                  // sum_e A1[e]B1[e]
      add(13,2,2, 0,1,2, 0,1,2, 1,1,1, 3);                  // sum_g A2[g]B2[g] (3 chunks)
      add(13,2,2, 3,4,5, 3,4,5, 1,1,1, 3);
      add(13,2,2, 6,7,8, 6,7,8, 1,1,1, 3);
    } else if (slot < 4) {
      const int m = slot - 1, p1 = (m+1)%3, p2 = (m+2)%3;
      add(1, 0,1, 0,0,0, m,0,0, 1,0,0, 1);                  // A0*B1[m]
      add(3, 1,0, m,0,0, 0,0,0, 1,0,0, 1);                  // A1[m]*B0
      add(6, 1,1, p1,p2,0, p2,p1,0, 1,-1,0, 2);             // eps(m,x,y)A1[x]B1[y]
      add(7, 1,2, 0,1,2, 3*m,3*m+1,3*m+2, 1,1,1, 3);        // sum_e A1[e]B2[m,e]
      add(10,2,1, 3*m,3*m+1,3*m+2, 0,1,2, 1,1,1, 3);        // sum_e A2[m,e]B1[e]
      add(14,2,2, 3*p1,3*p1+1,3*p1+2, 3*p2,3*p2+1,3*p2+2, 1,1,1, 3);    // +A2[p1,e]B2[p2,e]
      add(14,2,2, 3*p2,3*p2+1,3*p2+2, 3*p1,3*p1+1,3*p1+2, -1,-1,-1, 3); // -A2[p2,e]B2[p1,e]
    } else {
      const int m = slot - 4, uu = m/3, v = m%3, q1 = (v+1)%3, q2 = (v+2)%3;
      add(2, 0,2, 0,0,0, m,0,0, 1,0,0, 1);                  // A0*B2[u,v]
      add(4, 1,1, uu,0,0, v,0,0, 1,0,0, 1);                 // A1[u]*B1[v]
      add(8, 1,2, q1,q2,0, 3*uu+q2,3*uu+q1,0, 1,-1,0, 2);   // eps(v,x,y)A1[x]B2[u,y]
      add(9, 2,0, m,0,0, 0,0,0, 1,0,0, 1);                  // A2[u,v]*B0
      add(11,2,1, 3*uu+q1,3*uu+q2,0, q2,q1,0, 1,-1,0, 2);   // eps(v,e,f)A2[u,e]B1[f]
      add(12,2,2, 3*uu,3*uu+1,3*uu+2, 3*v,3*v+1,3*v+2, 1,1,1, 3); // sum_e A2[u,e]B2[v,e]
    }
    nch_s = n;
  }

  // one-time x2 staging: f32 -> f16 full-row table X2[z][f], coalesced float2
  for (int row = wid; row < 64; row += 8) {
    const float* __restrict__ src = x2 + (size_t)(zbase + row) * FEAT;
    _Float16* __restrict__ dst = X2 + row * X2S;
    #pragma unroll
    for (int k = 0; k < 7; ++k) {
      const int f = k * 128 + lane * 2;
      if (f < FEAT) {
        const float2 v = *(const float2*)(src + f);
        half2v h = { (_Float16)v.x, (_Float16)v.y };
        *(half2v*)(dst + f) = h;   // 4B-aligned: row*X2S even, f even
      }
    }
  }
  __syncthreads();
  const int nch = nch_s;

  floatx16 acc0, acc1;   // c-group 0 / 1 for this wave's (zg, a-quarter)
  #pragma unroll
  for (int r = 0; r < 16; ++r) { acc0[r] = 0.0f; acc1[r] = 0.0f; }

  for (int ci = 0; ci < nch; ++ci) {
    const Chunk C = chs[ci];  // block-uniform
    __syncthreads();          // previous chunk's XS1 readers done
    // stage x1 -> XS1 [t][a]*66+zz (pre-scaled by sg), 8 iters/thread
    #pragma unroll
    for (int t = 0; t < 3; ++t) {
      if (t < C.nt) {
        const float sgf = C.sg[t];
        const int o1 = C.o1[t];
        for (int e = tid; e < 4096; e += 512) {
          const int a = e & 63, zz = e >> 6;
          XS1[(t * 64 + a) * 66 + zz] =
              (_Float16)(x1[(size_t)(zbase + zz) * FEAT + o1 + a * C.d1] * sgf);
        }
      }
    }
    __syncthreads();

    const int key = C.nt * 16 + C.d2;
    switch (key) {
      case 17: run_chunk<1,1>(C, zl, hf, lane, a0, Wh, X2, XS1, acc0, acc1); break;
      case 19: run_chunk<1,3>(C, zl, hf, lane, a0, Wh, X2, XS1, acc0, acc1); break;
      case 25: run_chunk<1,9>(C, zl, hf, lane, a0, Wh, X2, XS1, acc0, acc1); break;
      case 35: run_chunk<2,3>(C, zl, hf, lane, a0, Wh, X2, XS1, acc0, acc1); break;
      case 41: run_chunk<2,9>(C, zl, hf, lane, a0, Wh, X2, XS1, acc0, acc1); break;
      case 51: run_chunk<3,3>(C, zl, hf, lane, a0, Wh, X2, XS1, acc0, acc1); break;
      default: run_chunk<3,9>(C, zl, hf, lane, a0, Wh, X2, XS1, acc0, acc1); break;
    }
  }

  // cross-wave reduction over a-quarters: aq>0 dump, aq==0 adds + stores.
  // Dv aliases X2 (all X2 reads done): 12 groups x 1024 f32 = 48 KB.
  __syncthreads();
  float* __restrict__ Dv = (float*)X2;
  if (aq > 0) {
    const int b0 = (((aq - 1) * 2 + zg) * 2 + 0) * 1024;
    const int b1 = (((aq - 1) * 2 + zg) * 2 + 1) * 1024;
    #pragma unroll
    for (int r = 0; r < 16; ++r) {
      Dv[b0 + r * 64 + lane] = acc0[r];
      Dv[b1 + r * 64 + lane] = acc1[r];
    }
  }
  __syncthreads();
  if (aq == 0) {
    #pragma unroll
    for (int j = 1; j < 4; ++j) {
      const int b0 = (((j - 1) * 2 + zg) * 2 + 0) * 1024;
      const int b1 = (((j - 1) * 2 + zg) * 2 + 1) * 1024;
      #pragma unroll
      for (int r = 0; r < 16; ++r) {
        acc0[r] += Dv[b0 + r * 64 + lane];
        acc1[r] += Dv[b1 + r * 64 + lane];
      }
    }
    // epilogue: C/D 32x32 layout: col(z)=lane&31, row(c)=(r&3)+8*(r>>2)+4*hf.
    float* __restrict__ op = out + (size_t)(zbase + zl) * FEAT + offO + mO;
    #pragma unroll
    for (int r = 0; r < 16; ++r) {
      const int cr = (r & 3) + 8 * (r >> 2) + 4 * hf;
      op[(size_t)cr * dO]        = acc0[r];
      op[(size_t)(cr + 32) * dO] = acc1[r];
    }
  }
}

extern "C" void kernel_launch(void* const* d_in, const int* in_sizes, int n_in,
                              void* d_out, int out_size, void* d_ws, size_t ws_size,
                              hipStream_t stream) {
  const float* x1 = (const float*)d_in[0];
  const float* x2 = (const float*)d_in[1];
  const float* w  = (const float*)d_in[2];
  float* out = (float*)d_out;
  _Float16* Wh = (_Float16*)d_ws;            // 15*64*4096 f16 = 7,864,320 B (swizzled)

  const int nchunks = 15 * 64 * 4096 / 8;    // 491520 half8 chunks
  hipLaunchKernelGGL(swz_w_kernel, dim3(nchunks / 256), dim3(256), 0, stream, w, Wh);

  hipLaunchKernelGGL(tp_kernel, dim3(832), dim3(512), 0, stream, x1, x2, Wh, out);
}